// Round 3
// baseline (534.163 us; speedup 1.0000x reference)
//
#include <hip/hip_runtime.h>
#include <stdint.h>

typedef unsigned short u16;
typedef __attribute__((ext_vector_type(8))) short bf16x8;   // 8 bf16 in 4 VGPRs (guide §3)
typedef __attribute__((ext_vector_type(8))) unsigned short u16x8;
typedef __attribute__((ext_vector_type(4))) unsigned short u16x4;
typedef __attribute__((ext_vector_type(4))) float f32x4;

#define TSEQ 2048
#define CDIM 2048
#define NHEAD 16
#define HDIM 128
#define NB 2
#define QKVROW (3 * CDIM)   // 6144 u16 per qkv row

__device__ __forceinline__ u16 f2bf(float f) {
  uint32_t u = __builtin_bit_cast(uint32_t, f);
  u += 0x7fffu + ((u >> 16) & 1u);          // RNE
  return (u16)(u >> 16);
}
__device__ __forceinline__ float bf2f(u16 h) {
  uint32_t u = ((uint32_t)h) << 16;
  return __builtin_bit_cast(float, u);
}

// async global->LDS, 16B per lane. LDS dest = wave-uniform base + lane*16.
// Direct addrspacecast (NOT integer truncation) so the compiler extracts the
// true LDS offset.
__device__ __forceinline__ void gload_lds16(const void* g, void* lds) {
  __builtin_amdgcn_global_load_lds(
      (const __attribute__((address_space(1))) uint32_t*)g,
      (__attribute__((address_space(3))) uint32_t*)lds,
      16, 0, 0);
}

// ---------------- cast fp32 -> bf16 (vectorized x4) ----------------
__global__ void cast_f32_bf16(const float* __restrict__ in, u16* __restrict__ out, int n4) {
  int i = blockIdx.x * blockDim.x + threadIdx.x;
  if (i >= n4) return;
  float4 v = ((const float4*)in)[i];
  u16x4 o;
  o[0] = f2bf(v.x); o[1] = f2bf(v.y); o[2] = f2bf(v.z); o[3] = f2bf(v.w);
  ((u16x4*)out)[i] = o;
}

// ---------------- bf16 GEMM, C = A[M,K] * B[N,K]^T ----------------
// m97 structure: 128x128 tile, BK=32, 4 waves (2x2), 16x16x32 MFMA, gload_lds width 16.
__device__ __forceinline__ void store_c(float* p, float v) { *p = v; }
__device__ __forceinline__ void store_c(u16* p, float v) { *p = f2bf(v); }

template <typename OutT>
__global__ __launch_bounds__(256) void gemm_bt(const u16* __restrict__ A,
                                               const u16* __restrict__ B,
                                               OutT* __restrict__ C,
                                               int M, int N, int K) {
  __shared__ u16 As[128 * 32];
  __shared__ u16 Bs[128 * 32];
  const int tid = threadIdx.x;
  const int lane = tid & 63;
  const int w = tid >> 6;
  const int wr = w >> 1, wc = w & 1;
  const int l15 = lane & 15, g = lane >> 4;
  const int m0 = blockIdx.y * 128, n0 = blockIdx.x * 128;

  f32x4 acc[4][4];
#pragma unroll
  for (int m = 0; m < 4; ++m)
#pragma unroll
    for (int n = 0; n < 4; ++n)
#pragma unroll
      for (int r = 0; r < 4; ++r) acc[m][n][r] = 0.f;

  for (int kt = 0; kt < K; kt += 32) {
    __syncthreads();  // previous tile's reads done before overwrite
#pragma unroll
    for (int i = 0; i < 2; ++i) {
      int c = i * 256 + tid;                 // chunk id; 8 bf16 per chunk
      int row = c >> 2, kk = (c & 3) * 8;
      gload_lds16(A + (size_t)(m0 + row) * K + kt + kk,
                  As + (size_t)(i * 256 + w * 64) * 8);
      gload_lds16(B + (size_t)(n0 + row) * K + kt + kk,
                  Bs + (size_t)(i * 256 + w * 64) * 8);
    }
    asm volatile("s_waitcnt vmcnt(0)" ::: "memory");
    __syncthreads();

    bf16x8 af[4], bfv[4];
#pragma unroll
    for (int m = 0; m < 4; ++m)
      af[m] = *(const bf16x8*)(As + (wr * 64 + m * 16 + l15) * 32 + g * 8);
#pragma unroll
    for (int n = 0; n < 4; ++n)
      bfv[n] = *(const bf16x8*)(Bs + (wc * 64 + n * 16 + l15) * 32 + g * 8);
#pragma unroll
    for (int m = 0; m < 4; ++m)
#pragma unroll
      for (int n = 0; n < 4; ++n)
        acc[m][n] = __builtin_amdgcn_mfma_f32_16x16x32_bf16(af[m], bfv[n], acc[m][n], 0, 0, 0);
  }

  // C/D layout: col = lane&15, row = (lane>>4)*4 + reg  [m89/m91]
#pragma unroll
  for (int m = 0; m < 4; ++m) {
    int row = m0 + wr * 64 + m * 16 + g * 4;
#pragma unroll
    for (int n = 0; n < 4; ++n) {
      int col = n0 + wc * 64 + n * 16 + l15;
#pragma unroll
      for (int r = 0; r < 4; ++r)
        store_c(C + (size_t)(row + r) * N + col, acc[m][n][r]);
    }
  }
}

// ---------------- RoPE in-place on qkv [B,T,3C] ----------------
// One thread per (b,t,h,i), i in [0,64): rotates the (i, i+64) pair of q and
// of k in place. Scale 1/sqrt(D) folded into q. v untouched.
__global__ void rope_inplace(u16* __restrict__ qkv) {
  int idx = blockIdx.x * 256 + threadIdx.x;
  int i = idx & 63;
  int h = (idx >> 6) & (NHEAD - 1);
  int t = (idx >> 10) & (TSEQ - 1);
  int b = idx >> 21;
  size_t rowb = (size_t)(b * TSEQ + t) * QKVROW;
  int col = h * HDIM + i;
  float q1 = bf2f(qkv[rowb + col]);
  float q2 = bf2f(qkv[rowb + col + 64]);
  float k1 = bf2f(qkv[rowb + CDIM + col]);
  float k2 = bf2f(qkv[rowb + CDIM + col + 64]);

  float inv = powf(10000.0f, -(float)i * (1.0f / 64.0f));
  float ang = (float)t * inv;
  float sn, cs;
  sincosf(ang, &sn, &cs);

  const float scale = 0.08838834764831845f;  // 1/sqrt(128)
  qkv[rowb + col]              = f2bf((q1 * cs - q2 * sn) * scale);
  qkv[rowb + col + 64]         = f2bf((q2 * cs + q1 * sn) * scale);
  qkv[rowb + CDIM + col]       = f2bf(k1 * cs - k2 * sn);
  qkv[rowb + CDIM + col + 64]  = f2bf(k2 * cs + k1 * sn);
}

// ---------------- causal flash attention (reads strided qkv) ----------------
// Block: 256 thr (4 waves). Q tile = 64 rows (16/wave), KV tiles of 64.
// Q/K LDS tiles [64][128] bf16, XOR-swizzled byte^((row&7)<<4) via pre-swizzled
// global source (m173). V reg-staged transposed into Vt[128][64] with swizzle
// ((d^(d>>3))&7)<<4 (write & read both <=2-way). P via per-wave LDS region.
__global__ __launch_bounds__(256) void attn(const u16* __restrict__ qkv,
                                            u16* __restrict__ Og) {
  __shared__ u16 Qs[64 * 128];   // reused as P region after q-frags hoisted
  __shared__ u16 Ks[64 * 128];
  __shared__ u16 Vt[128 * 64];
  const int tid = threadIdx.x;
  const int lane = tid & 63;
  const int w = tid >> 6;
  const int l15 = lane & 15, g = lane >> 4;
  const int qt = blockIdx.x;
  const int q0 = qt * 64;
  const int bh = blockIdx.y;
  const int b = bh >> 4, h = bh & (NHEAD - 1);
  // strided bases inside qkv (u16 elements); row stride = QKVROW
  const u16* Qb = qkv + (size_t)(b * TSEQ) * QKVROW + h * HDIM;
  const u16* Kb = Qb + CDIM;
  const u16* Vb = Qb + 2 * CDIM;

  // stage Q: chunk c covers LDS bytes [c*16, c*16+16); LDS row = c>>4 (256 B
  // rows), in-row byte = (c&15)*16, XOR'd by ((row&7)<<4) via the SOURCE addr.
#pragma unroll
  for (int i = 0; i < 4; ++i) {
    int c = i * 256 + tid;
    int row = c >> 4;
    int irb = ((c & 15) * 16) ^ ((row & 7) << 4);
    gload_lds16((const char*)(Qb + (size_t)(q0 + row) * QKVROW) + irb,
                (char*)Qs + (i * 256 + w * 64) * 16);
  }
  asm volatile("s_waitcnt vmcnt(0)" ::: "memory");
  __syncthreads();

  // hoist Q fragments to registers (A-frag: row=lane&15, k=(lane>>4)*8)
  bf16x8 qf[4];
#pragma unroll
  for (int dk = 0; dk < 4; ++dk) {
    int row = w * 16 + l15;
    int byte = row * 256 + dk * 64 + g * 16;
    byte ^= ((row & 7) << 4);
    qf[dk] = *(const bf16x8*)((const char*)Qs + byte);
  }

  float mrow[4], lrow[4];
  f32x4 oacc[8];
#pragma unroll
  for (int r = 0; r < 4; ++r) { mrow[r] = -1e30f; lrow[r] = 0.f; }
#pragma unroll
  for (int f = 0; f < 8; ++f)
#pragma unroll
    for (int r = 0; r < 4; ++r) oacc[f][r] = 0.f;

  u16* Ps = Qs;  // per-wave 16x64 bf16 region at w*2048 bytes

  for (int ti = 0; ti <= qt; ++ti) {
    const int k0 = ti * 64;
    __syncthreads();  // prior tile's LDS reads done
    // stage K (same pattern as Q)
#pragma unroll
    for (int i = 0; i < 4; ++i) {
      int c = i * 256 + tid;
      int row = c >> 4;
      int irb = ((c & 15) * 16) ^ ((row & 7) << 4);
      gload_lds16((const char*)(Kb + (size_t)(k0 + row) * QKVROW) + irb,
                  (char*)Ks + (i * 256 + w * 64) * 16);
    }
    // stage V transposed (reg path)
#pragma unroll
    for (int i = 0; i < 4; ++i) {
      int c = i * 256 + tid;
      int kr = c >> 4;
      int d0 = (c & 15) * 8;
      u16x8 v = *(const u16x8*)(Vb + (size_t)(k0 + kr) * QKVROW + d0);
#pragma unroll
      for (int j = 0; j < 8; ++j) {
        int d = d0 + j;
        int byte = d * 128 + kr * 2;
        byte ^= (((d ^ (d >> 3)) & 7) << 4);
        *(u16*)((char*)Vt + byte) = v[j];
      }
    }
    asm volatile("s_waitcnt vmcnt(0)" ::: "memory");
    __syncthreads();

    // S = Q K^T : per wave 16 q-rows x 64 kv
    f32x4 sfr[4];
#pragma unroll
    for (int jf = 0; jf < 4; ++jf)
#pragma unroll
      for (int r = 0; r < 4; ++r) sfr[jf][r] = 0.f;
#pragma unroll
    for (int dk = 0; dk < 4; ++dk) {
#pragma unroll
      for (int jf = 0; jf < 4; ++jf) {
        int row = jf * 16 + l15;
        int byte = row * 256 + dk * 64 + g * 16;
        byte ^= ((row & 7) << 4);
        bf16x8 kf = *(const bf16x8*)((const char*)Ks + byte);
        sfr[jf] = __builtin_amdgcn_mfma_f32_16x16x32_bf16(qf[dk], kf, sfr[jf], 0, 0, 0);
      }
    }
    // causal mask (diagonal tile only; k0 == q0)
    if (ti == qt) {
#pragma unroll
      for (int jf = 0; jf < 4; ++jf) {
        int colg = jf * 16 + l15;
#pragma unroll
        for (int r = 0; r < 4; ++r) {
          int rowg = w * 16 + g * 4 + r;
          if (colg > rowg) sfr[jf][r] = -1e30f;
        }
      }
    }
    // online softmax (rows live in 16-lane groups; shfl_xor 1/2/4/8 reduces)
    float al[4];
#pragma unroll
    for (int r = 0; r < 4; ++r) {
      float pm = fmaxf(fmaxf(sfr[0][r], sfr[1][r]), fmaxf(sfr[2][r], sfr[3][r]));
      pm = fmaxf(pm, __shfl_xor(pm, 1));
      pm = fmaxf(pm, __shfl_xor(pm, 2));
      pm = fmaxf(pm, __shfl_xor(pm, 4));
      pm = fmaxf(pm, __shfl_xor(pm, 8));
      float mn = fmaxf(mrow[r], pm);
      al[r] = __expf(mrow[r] - mn);
      mrow[r] = mn;
    }
    float psum[4] = {0.f, 0.f, 0.f, 0.f};
#pragma unroll
    for (int jf = 0; jf < 4; ++jf)
#pragma unroll
      for (int r = 0; r < 4; ++r) {
        float p = __expf(sfr[jf][r] - mrow[r]);
        sfr[jf][r] = p;
        psum[r] += p;
      }
#pragma unroll
    for (int r = 0; r < 4; ++r) {
      float s = psum[r];
      s += __shfl_xor(s, 1);
      s += __shfl_xor(s, 2);
      s += __shfl_xor(s, 4);
      s += __shfl_xor(s, 8);
      lrow[r] = lrow[r] * al[r] + s;
#pragma unroll
      for (int f = 0; f < 8; ++f) oacc[f][r] *= al[r];
    }
    // P -> LDS bf16 (own wave region), swizzled by row
#pragma unroll
    for (int jf = 0; jf < 4; ++jf)
#pragma unroll
      for (int r = 0; r < 4; ++r) {
        int row = g * 4 + r;
        int byte = w * 2048 + row * 128 + (jf * 16 + l15) * 2;
        byte ^= ((row & 7) << 4);
        *(u16*)((char*)Ps + byte) = f2bf(sfr[jf][r]);
      }
    // O += P V
#pragma unroll
    for (int ks = 0; ks < 2; ++ks) {
      int pbyte = w * 2048 + l15 * 128 + ks * 64 + g * 16;
      pbyte ^= ((l15 & 7) << 4);
      bf16x8 pa = *(const bf16x8*)((const char*)Ps + pbyte);
#pragma unroll
      for (int df = 0; df < 8; ++df) {
        int d = df * 16 + l15;
        int vbyte = d * 128 + ks * 64 + g * 16;
        vbyte ^= (((d ^ (d >> 3)) & 7) << 4);
        bf16x8 vf = *(const bf16x8*)((const char*)Vt + vbyte);
        oacc[df] = __builtin_amdgcn_mfma_f32_16x16x32_bf16(pa, vf, oacc[df], 0, 0, 0);
      }
    }
  }

  // epilogue: O /= l, write [B,T,H*D] bf16
#pragma unroll
  for (int r = 0; r < 4; ++r) {
    float inv = 1.0f / lrow[r];
    int trow = q0 + w * 16 + g * 4 + r;
    size_t base = ((size_t)(b * TSEQ + trow)) * CDIM + h * HDIM;
#pragma unroll
    for (int df = 0; df < 8; ++df)
      Og[base + df * 16 + l15] = f2bf(oacc[df][r] * inv);
  }
}

// ---------------- launch ----------------
extern "C" void kernel_launch(void* const* d_in, const int* in_sizes, int n_in,
                              void* d_out, int out_size, void* d_ws, size_t ws_size,
                              hipStream_t stream) {
  const float* x = (const float*)d_in[0];      // [2,2048,2048]
  const float* wqkv = (const float*)d_in[1];   // [6144,2048]
  const float* wo = (const float*)d_in[2];     // [2048,2048]
  float* out = (float*)d_out;                  // [2,2048,2048] fp32

  const size_t M = (size_t)NB * TSEQ;          // 4096
  char* ws = (char*)d_ws;
  u16* wqkvb = (u16*)ws;  ws += (size_t)3 * CDIM * CDIM * 2;  // 24 MiB
  u16* wob   = (u16*)ws;  ws += (size_t)CDIM * CDIM * 2;      //  8 MiB
  u16* qkvb  = (u16*)ws;  ws += M * QKVROW * 2;               // 48 MiB
  u16* xb    = (u16*)ws;  ws += M * CDIM * 2;                 // 16 MiB
  u16* Og    = xb;  // alias: xb dead after GEMM1; attn reads qkvb, writes here
  const size_t needed = (size_t)(ws - (char*)d_ws);           // 96 MiB
  if (ws_size < needed) return;  // guard: never write OOB scratch

  // casts
  cast_f32_bf16<<<(M * CDIM / 4 + 255) / 256, 256, 0, stream>>>(x, xb, (int)(M * CDIM / 4));
  cast_f32_bf16<<<(3 * CDIM * CDIM / 4 + 255) / 256, 256, 0, stream>>>(wqkv, wqkvb, 3 * CDIM * CDIM / 4);
  cast_f32_bf16<<<(CDIM * CDIM / 4 + 255) / 256, 256, 0, stream>>>(wo, wob, CDIM * CDIM / 4);

  // qkv = x * wqkv^T   (M=4096, N=6144, K=2048)
  gemm_bt<u16><<<dim3(3 * CDIM / 128, M / 128), 256, 0, stream>>>(xb, wqkvb, qkvb,
                                                                  (int)M, 3 * CDIM, CDIM);
  // rope in place on q,k sections
  rope_inplace<<<(NB * TSEQ * NHEAD * 64) / 256, 256, 0, stream>>>(qkvb);

  // flash attention (strided reads from qkvb)
  attn<<<dim3(TSEQ / 64, NB * NHEAD), 256, 0, stream>>>(qkvb, Og);

  // out = O * wo^T   (M=4096, N=2048, K=2048)
  gemm_bt<float><<<dim3(CDIM / 128, M / 128), 256, 0, stream>>>(Og, wob, out,
                                                                (int)M, CDIM, CDIM);
}

// Round 5
// 500.337 us; speedup vs baseline: 1.0676x; 1.0676x over previous
//
#include <hip/hip_runtime.h>
#include <stdint.h>

typedef unsigned short u16;
typedef __attribute__((ext_vector_type(8))) short bf16x8;   // 8 bf16 in 4 VGPRs
typedef __attribute__((ext_vector_type(8))) unsigned short u16x8;
typedef __attribute__((ext_vector_type(4))) unsigned short u16x4;
typedef __attribute__((ext_vector_type(4))) float f32x4;

#define TSEQ 2048
#define CDIM 2048
#define NHEAD 16
#define HDIM 128
#define NB 2
#define QKVROW (3 * CDIM)   // 6144 u16 per qkv row

__device__ __forceinline__ u16 f2bf(float f) {
  uint32_t u = __builtin_bit_cast(uint32_t, f);
  u += 0x7fffu + ((u >> 16) & 1u);          // RNE
  return (u16)(u >> 16);
}
__device__ __forceinline__ float bf2f(u16 h) {
  uint32_t u = ((uint32_t)h) << 16;
  return __builtin_bit_cast(float, u);
}

// async global->LDS, 16B per lane. LDS dest = wave-uniform base + lane*16.
__device__ __forceinline__ void gload_lds16(const void* g, void* lds) {
  __builtin_amdgcn_global_load_lds(
      (const __attribute__((address_space(1))) uint32_t*)g,
      (__attribute__((address_space(3))) uint32_t*)lds,
      16, 0, 0);
}

// ---- DPP 16-lane reductions (VALU-speed, no LDS traffic) ----
// ctrl: 0xB1=quad_perm[1,0,3,2] (xor1), 0x4E=quad_perm[2,3,0,1] (xor2),
// 0x141=row_half_mirror (combines 4-groups), 0x140=row_mirror (combines 8-groups).
template <int CTRL>
__device__ __forceinline__ float dpp_mov(float x) {
  int t = __builtin_amdgcn_update_dpp(0, __builtin_bit_cast(int, x), CTRL, 0xf, 0xf, true);
  return __builtin_bit_cast(float, t);
}
__device__ __forceinline__ float red_max16(float x) {
  x = fmaxf(x, dpp_mov<0xB1>(x));
  x = fmaxf(x, dpp_mov<0x4E>(x));
  x = fmaxf(x, dpp_mov<0x141>(x));
  x = fmaxf(x, dpp_mov<0x140>(x));
  return x;
}
__device__ __forceinline__ float red_sum16(float x) {
  x += dpp_mov<0xB1>(x);
  x += dpp_mov<0x4E>(x);
  x += dpp_mov<0x141>(x);
  x += dpp_mov<0x140>(x);
  return x;
}

// ---------------- cast fp32 -> bf16 (vectorized x4) ----------------
__global__ void cast_f32_bf16(const float* __restrict__ in, u16* __restrict__ out, int n4) {
  int i = blockIdx.x * blockDim.x + threadIdx.x;
  if (i >= n4) return;
  float4 v = ((const float4*)in)[i];
  u16x4 o;
  o[0] = f2bf(v.x); o[1] = f2bf(v.y); o[2] = f2bf(v.z); o[3] = f2bf(v.w);
  ((u16x4*)out)[i] = o;
}

// ---------------- bf16 GEMM, C = A[M,K] * B[N,K]^T ----------------
// m97 structure: 128x128 tile, BK=32, 4 waves (2x2), 16x16x32 MFMA, gload_lds width 16.
__device__ __forceinline__ void store_c(float* p, float v) { *p = v; }
__device__ __forceinline__ void store_c(u16* p, float v) { *p = f2bf(v); }

template <typename OutT>
__global__ __launch_bounds__(256) void gemm_bt(const u16* __restrict__ A,
                                               const u16* __restrict__ B,
                                               OutT* __restrict__ C,
                                               int M, int N, int K) {
  __shared__ u16 As[128 * 32];
  __shared__ u16 Bs[128 * 32];
  const int tid = threadIdx.x;
  const int lane = tid & 63;
  const int w = tid >> 6;
  const int wr = w >> 1, wc = w & 1;
  const int l15 = lane & 15, g = lane >> 4;
  const int m0 = blockIdx.y * 128, n0 = blockIdx.x * 128;

  f32x4 acc[4][4];
#pragma unroll
  for (int m = 0; m < 4; ++m)
#pragma unroll
    for (int n = 0; n < 4; ++n)
#pragma unroll
      for (int r = 0; r < 4; ++r) acc[m][n][r] = 0.f;

  for (int kt = 0; kt < K; kt += 32) {
    __syncthreads();  // previous tile's reads done before overwrite
#pragma unroll
    for (int i = 0; i < 2; ++i) {
      int c = i * 256 + tid;                 // chunk id; 8 bf16 per chunk
      int row = c >> 2, kk = (c & 3) * 8;
      gload_lds16(A + (size_t)(m0 + row) * K + kt + kk,
                  As + (size_t)(i * 256 + w * 64) * 8);
      gload_lds16(B + (size_t)(n0 + row) * K + kt + kk,
                  Bs + (size_t)(i * 256 + w * 64) * 8);
    }
    asm volatile("s_waitcnt vmcnt(0)" ::: "memory");
    __syncthreads();

    bf16x8 af[4], bfv[4];
#pragma unroll
    for (int m = 0; m < 4; ++m)
      af[m] = *(const bf16x8*)(As + (wr * 64 + m * 16 + l15) * 32 + g * 8);
#pragma unroll
    for (int n = 0; n < 4; ++n)
      bfv[n] = *(const bf16x8*)(Bs + (wc * 64 + n * 16 + l15) * 32 + g * 8);
#pragma unroll
    for (int m = 0; m < 4; ++m)
#pragma unroll
      for (int n = 0; n < 4; ++n)
        acc[m][n] = __builtin_amdgcn_mfma_f32_16x16x32_bf16(af[m], bfv[n], acc[m][n], 0, 0, 0);
  }

  // C/D layout: col = lane&15, row = (lane>>4)*4 + reg  [m89/m91]
#pragma unroll
  for (int m = 0; m < 4; ++m) {
    int row = m0 + wr * 64 + m * 16 + g * 4;
#pragma unroll
    for (int n = 0; n < 4; ++n) {
      int col = n0 + wc * 64 + n * 16 + l15;
#pragma unroll
      for (int r = 0; r < 4; ++r)
        store_c(C + (size_t)(row + r) * N + col, acc[m][n][r]);
    }
  }
}

// ---------------- RoPE in-place on qkv [B,T,3C] ----------------
__global__ void rope_inplace(u16* __restrict__ qkv) {
  int idx = blockIdx.x * 256 + threadIdx.x;
  int i = idx & 63;
  int h = (idx >> 6) & (NHEAD - 1);
  int t = (idx >> 10) & (TSEQ - 1);
  int b = idx >> 21;
  size_t rowb = (size_t)(b * TSEQ + t) * QKVROW;
  int col = h * HDIM + i;
  float q1 = bf2f(qkv[rowb + col]);
  float q2 = bf2f(qkv[rowb + col + 64]);
  float k1 = bf2f(qkv[rowb + CDIM + col]);
  float k2 = bf2f(qkv[rowb + CDIM + col + 64]);

  float inv = powf(10000.0f, -(float)i * (1.0f / 64.0f));
  float ang = (float)t * inv;
  float sn, cs;
  sincosf(ang, &sn, &cs);

  const float scale = 0.08838834764831845f;  // 1/sqrt(128)
  qkv[rowb + col]              = f2bf((q1 * cs - q2 * sn) * scale);
  qkv[rowb + col + 64]         = f2bf((q2 * cs + q1 * sn) * scale);
  qkv[rowb + CDIM + col]       = f2bf(k1 * cs - k2 * sn);
  qkv[rowb + CDIM + col + 64]  = f2bf(k2 * cs + k1 * sn);
}

// ---------------- causal flash attention (pipelined, strided qkv) -----------
// 256 thr (4 waves). Q tile = 64 rows (16/wave), KV tiles of 64.
// T14 split: tile t+1's K/V global loads issued BEFORE compute(t); ds_writes
// after the compute barrier (latency hidden under ~600cy of MFMA/VALU).
// K LDS [64][128] bf16 XOR-swizzled byte^((row&7)<<4) (swizzle at source addr,
// linear LDS write). V transposed Vt[128][64] swizzle ((d^(d>>3))&7)<<4,
// packed ds_write_b64. Softmax reduction via DPP. P via per-wave LDS region.
__global__ __launch_bounds__(256) void attn(const u16* __restrict__ qkv,
                                            u16* __restrict__ Og) {
  __shared__ u16 Qs[64 * 128];   // wave w's rows [w*16, w*16+16) reused as its P region
  __shared__ u16 Ks[64 * 128];
  __shared__ u16 Vt[128 * 64];
  const int tid = threadIdx.x;
  const int lane = tid & 63;
  const int w = tid >> 6;
  const int l15 = lane & 15, g = lane >> 4;
  const int qt = (int)gridDim.x - 1 - (int)blockIdx.x;  // heavy blocks dispatch first
  const int q0 = qt * 64;
  const int bh = blockIdx.y;
  const int b = bh >> 4, h = bh & (NHEAD - 1);
  const u16* Qb = qkv + (size_t)(b * TSEQ) * QKVROW + h * HDIM;
  const u16* Kb = Qb + CDIM;
  const u16* Vb = Qb + 2 * CDIM;

  // V staging geometry: unit per thread: kv4 = tid&15 (4 kv rows), d0 = (tid>>4)*8
  const int v_kv4 = tid & 15;
  const int v_d0 = (tid >> 4) * 8;

  // ---- prologue ----
  // stage Q via gload_lds (pre-swizzled source -> linear LDS == swizzled layout)
#pragma unroll
  for (int i = 0; i < 4; ++i) {
    int c = i * 256 + tid;
    int row = c >> 4;
    int irb = ((c & 15) * 16) ^ ((row & 7) << 4);
    gload_lds16((const char*)(Qb + (size_t)(q0 + row) * QKVROW) + irb,
                (char*)Qs + (i * 256 + w * 64) * 16);
  }
  // issue K/V tile-0 loads into regs
  u16x8 kreg[4], vreg[4];
#pragma unroll
  for (int i = 0; i < 4; ++i) {
    int c = i * 256 + tid;
    int row = c >> 4;
    int irb = ((c & 15) * 16) ^ ((row & 7) << 4);
    kreg[i] = *(const u16x8*)((const char*)(Kb + (size_t)row * QKVROW) + irb);
  }
#pragma unroll
  for (int jj = 0; jj < 4; ++jj)
    vreg[jj] = *(const u16x8*)(Vb + (size_t)(v_kv4 * 4 + jj) * QKVROW + v_d0);

  asm volatile("s_waitcnt vmcnt(0)" ::: "memory");  // Q gload drained
  __syncthreads();

  // hoist Q fragments (A-frag: row=lane&15, k=(lane>>4)*8) — own wave's rows only
  bf16x8 qf[4];
#pragma unroll
  for (int dk = 0; dk < 4; ++dk) {
    int row = w * 16 + l15;
    int byte = row * 256 + dk * 64 + g * 16;
    byte ^= ((row & 7) << 4);
    qf[dk] = *(const bf16x8*)((const char*)Qs + byte);
  }

  // write tile-0 K/V to LDS
#pragma unroll
  for (int i = 0; i < 4; ++i) {
    int c = i * 256 + tid;
    *(u16x8*)((char*)Ks + c * 16) = kreg[i];
  }
#pragma unroll
  for (int j = 0; j < 8; ++j) {
    int d = v_d0 + j;
    int byte = d * 128 + v_kv4 * 8;
    byte ^= (((d ^ (d >> 3)) & 7) << 4);
    u16x4 p;
    p[0] = vreg[0][j]; p[1] = vreg[1][j]; p[2] = vreg[2][j]; p[3] = vreg[3][j];
    *(u16x4*)((char*)Vt + byte) = p;
  }
  __syncthreads();

  float mrow[4], lrow[4];
  f32x4 oacc[8];
#pragma unroll
  for (int r = 0; r < 4; ++r) { mrow[r] = -1e30f; lrow[r] = 0.f; }
#pragma unroll
  for (int f = 0; f < 8; ++f)
#pragma unroll
    for (int r = 0; r < 4; ++r) oacc[f][r] = 0.f;

  u16* Ps = Qs;  // per-wave 16x64 bf16 region at w*2048 bytes

  for (int ti = 0; ti <= qt; ++ti) {
    // ---- prefetch next tile into regs (latency hides under compute below) ----
    if (ti < qt) {
      const int kn = (ti + 1) * 64;
#pragma unroll
      for (int i = 0; i < 4; ++i) {
        int c = i * 256 + tid;
        int row = c >> 4;
        int irb = ((c & 15) * 16) ^ ((row & 7) << 4);
        kreg[i] = *(const u16x8*)((const char*)(Kb + (size_t)(kn + row) * QKVROW) + irb);
      }
#pragma unroll
      for (int jj = 0; jj < 4; ++jj)
        vreg[jj] = *(const u16x8*)(Vb + (size_t)(kn + v_kv4 * 4 + jj) * QKVROW + v_d0);
    }

    // ---- S = Q K^T : per wave 16 q-rows x 64 kv ----
    f32x4 sfr[4];
#pragma unroll
    for (int jf = 0; jf < 4; ++jf)
#pragma unroll
      for (int r = 0; r < 4; ++r) sfr[jf][r] = 0.f;
#pragma unroll
    for (int dk = 0; dk < 4; ++dk) {
#pragma unroll
      for (int jf = 0; jf < 4; ++jf) {
        int row = jf * 16 + l15;
        int byte = row * 256 + dk * 64 + g * 16;
        byte ^= ((row & 7) << 4);
        bf16x8 kf = *(const bf16x8*)((const char*)Ks + byte);
        sfr[jf] = __builtin_amdgcn_mfma_f32_16x16x32_bf16(qf[dk], kf, sfr[jf], 0, 0, 0);
      }
    }
    // causal mask (diagonal tile only)
    if (ti == qt) {
#pragma unroll
      for (int jf = 0; jf < 4; ++jf) {
        int colg = jf * 16 + l15;
#pragma unroll
        for (int r = 0; r < 4; ++r) {
          int rowg = w * 16 + g * 4 + r;
          if (colg > rowg) sfr[jf][r] = -1e30f;
        }
      }
    }
    // ---- online softmax (DPP reductions over the 16-lane row group) ----
    float al[4];
#pragma unroll
    for (int r = 0; r < 4; ++r) {
      float pm = fmaxf(fmaxf(sfr[0][r], sfr[1][r]), fmaxf(sfr[2][r], sfr[3][r]));
      pm = red_max16(pm);
      float mn = fmaxf(mrow[r], pm);
      al[r] = __expf(mrow[r] - mn);
      mrow[r] = mn;
    }
    float psum[4] = {0.f, 0.f, 0.f, 0.f};
#pragma unroll
    for (int jf = 0; jf < 4; ++jf)
#pragma unroll
      for (int r = 0; r < 4; ++r) {
        float p = __expf(sfr[jf][r] - mrow[r]);
        sfr[jf][r] = p;
        psum[r] += p;
      }
#pragma unroll
    for (int r = 0; r < 4; ++r) {
      float s = red_sum16(psum[r]);
      lrow[r] = lrow[r] * al[r] + s;
#pragma unroll
      for (int f = 0; f < 8; ++f) oacc[f][r] *= al[r];
    }
    // P -> LDS bf16 (own wave region), swizzled by row
#pragma unroll
    for (int jf = 0; jf < 4; ++jf)
#pragma unroll
      for (int r = 0; r < 4; ++r) {
        int row = g * 4 + r;
        int byte = w * 2048 + row * 128 + (jf * 16 + l15) * 2;
        byte ^= ((row & 7) << 4);
        *(u16*)((char*)Ps + byte) = f2bf(sfr[jf][r]);
      }
    // ---- O += P V ----
#pragma unroll
    for (int ks = 0; ks < 2; ++ks) {
      int pbyte = w * 2048 + l15 * 128 + ks * 64 + g * 16;
      pbyte ^= ((l15 & 7) << 4);
      bf16x8 pa = *(const bf16x8*)((const char*)Ps + pbyte);
#pragma unroll
      for (int df = 0; df < 8; ++df) {
        int d = df * 16 + l15;
        int vbyte = d * 128 + ks * 64 + g * 16;
        vbyte ^= (((d ^ (d >> 3)) & 7) << 4);
        bf16x8 vf = *(const bf16x8*)((const char*)Vt + vbyte);
        oacc[df] = __builtin_amdgcn_mfma_f32_16x16x32_bf16(pa, vf, oacc[df], 0, 0, 0);
      }
    }

    // ---- publish next tile to LDS (loads completed during compute) ----
    __syncthreads();  // everyone done reading Ks/Vt
    if (ti < qt) {
#pragma unroll
      for (int i = 0; i < 4; ++i) {
        int c = i * 256 + tid;
        *(u16x8*)((char*)Ks + c * 16) = kreg[i];
      }
#pragma unroll
      for (int j = 0; j < 8; ++j) {
        int d = v_d0 + j;
        int byte = d * 128 + v_kv4 * 8;
        byte ^= (((d ^ (d >> 3)) & 7) << 4);
        u16x4 p;
        p[0] = vreg[0][j]; p[1] = vreg[1][j]; p[2] = vreg[2][j]; p[3] = vreg[3][j];
        *(u16x4*)((char*)Vt + byte) = p;
      }
    }
    __syncthreads();  // next tile visible
  }

  // epilogue: O /= l, write [B,T,H*D] bf16
#pragma unroll
  for (int r = 0; r < 4; ++r) {
    float inv = 1.0f / lrow[r];
    int trow = q0 + w * 16 + g * 4 + r;
    size_t base = ((size_t)(b * TSEQ + trow)) * CDIM + h * HDIM;
#pragma unroll
    for (int df = 0; df < 8; ++df)
      Og[base + df * 16 + l15] = f2bf(oacc[df][r] * inv);
  }
}

// ---------------- launch ----------------
extern "C" void kernel_launch(void* const* d_in, const int* in_sizes, int n_in,
                              void* d_out, int out_size, void* d_ws, size_t ws_size,
                              hipStream_t stream) {
  const float* x = (const float*)d_in[0];      // [2,2048,2048]
  const float* wqkv = (const float*)d_in[1];   // [6144,2048]
  const float* wo = (const float*)d_in[2];     // [2048,2048]
  float* out = (float*)d_out;                  // [2,2048,2048] fp32

  const size_t M = (size_t)NB * TSEQ;          // 4096
  char* ws = (char*)d_ws;
  u16* wqkvb = (u16*)ws;  ws += (size_t)3 * CDIM * CDIM * 2;  // 24 MiB
  u16* wob   = (u16*)ws;  ws += (size_t)CDIM * CDIM * 2;      //  8 MiB
  u16* qkvb  = (u16*)ws;  ws += M * QKVROW * 2;               // 48 MiB
  u16* xb    = (u16*)ws;  ws += M * CDIM * 2;                 // 16 MiB
  u16* Og    = xb;  // alias: xb dead after GEMM1; attn reads qkvb, writes here
  const size_t needed = (size_t)(ws - (char*)d_ws);           // 96 MiB
  if (ws_size < needed) return;  // guard: never write OOB scratch

  // casts
  cast_f32_bf16<<<(M * CDIM / 4 + 255) / 256, 256, 0, stream>>>(x, xb, (int)(M * CDIM / 4));
  cast_f32_bf16<<<(3 * CDIM * CDIM / 4 + 255) / 256, 256, 0, stream>>>(wqkv, wqkvb, 3 * CDIM * CDIM / 4);
  cast_f32_bf16<<<(CDIM * CDIM / 4 + 255) / 256, 256, 0, stream>>>(wo, wob, CDIM * CDIM / 4);

  // qkv = x * wqkv^T   (M=4096, N=6144, K=2048)
  gemm_bt<u16><<<dim3(3 * CDIM / 128, M / 128), 256, 0, stream>>>(xb, wqkvb, qkvb,
                                                                  (int)M, 3 * CDIM, CDIM);
  // rope in place on q,k sections
  rope_inplace<<<(NB * TSEQ * NHEAD * 64) / 256, 256, 0, stream>>>(qkvb);

  // flash attention (strided reads from qkvb)
  attn<<<dim3(TSEQ / 64, NB * NHEAD), 256, 0, stream>>>(qkvb, Og);

  // out = O * wo^T   (M=4096, N=2048, K=2048)
  gemm_bt<float><<<dim3(CDIM / 128, M / 128), 256, 0, stream>>>(Og, wob, out,
                                                                (int)M, CDIM, CDIM);
}